// Round 2
// baseline (258.161 us; speedup 1.0000x reference)
//
#include <hip/hip_runtime.h>

#define NJ 19
#define ROOT_SCALE 200.0f
#define BLOCK 256

struct Xform { float r[9]; float t[3]; };

__device__ __forceinline__ void quat_rt(float w, float x, float y, float z,
                                        float tx, float ty, float tz, Xform& o) {
    float ts = 2.0f / (w*w + x*x + y*y + z*z);
    o.r[0] = 1.0f - ts*(y*y + z*z); o.r[1] = ts*(x*y - z*w);        o.r[2] = ts*(x*z + y*w);
    o.r[3] = ts*(x*y + z*w);        o.r[4] = 1.0f - ts*(x*x + z*z); o.r[5] = ts*(y*z - x*w);
    o.r[6] = ts*(x*z - y*w);        o.r[7] = ts*(y*z + x*w);        o.r[8] = 1.0f - ts*(x*x + y*y);
    o.t[0] = o.r[0]*tx + o.r[1]*ty + o.r[2]*tz;
    o.t[1] = o.r[3]*tx + o.r[4]*ty + o.r[5]*tz;
    o.t[2] = o.r[6]*tx + o.r[7]*ty + o.r[8]*tz;
}

// o = p ∘ l  (rigid compose): o.r = p.r*l.r ; o.t = p.r*l.t + p.t
__device__ __forceinline__ void compose(const Xform& p, const Xform& l, Xform& o) {
#pragma unroll
    for (int i = 0; i < 3; ++i) {
        o.r[i*3+0] = p.r[i*3+0]*l.r[0] + p.r[i*3+1]*l.r[3] + p.r[i*3+2]*l.r[6];
        o.r[i*3+1] = p.r[i*3+0]*l.r[1] + p.r[i*3+1]*l.r[4] + p.r[i*3+2]*l.r[7];
        o.r[i*3+2] = p.r[i*3+0]*l.r[2] + p.r[i*3+1]*l.r[5] + p.r[i*3+2]*l.r[8];
        o.t[i]     = p.r[i*3+0]*l.t[0] + p.r[i*3+1]*l.t[1] + p.r[i*3+2]*l.t[2] + p.t[i];
    }
}

// No LDS, no barriers: each thread owns one batch row end-to-end.
// Lane j-loop loads are contiguous within the lane (304B span, ~4 loads per
// 64B line -> L1/MSHR absorbs the reuse); occupancy is VGPR-bound only.
__global__ __launch_bounds__(BLOCK) void fk_kernel(
    const float* __restrict__ root, const float* __restrict__ joint,
    const float* __restrict__ offs, float* __restrict__ out, int batch)
{
    const int b = blockIdx.x * BLOCK + threadIdx.x;
    if (b >= batch) return;

    const float4* jq = (const float4*)joint + (long long)b * NJ;
    float4*       op = (float4*)out        + (long long)b * NJ;

    const float rx = root[(long long)b*3 + 0] * ROOT_SCALE;
    const float ry = root[(long long)b*3 + 1] * ROOT_SCALE;
    const float rz = root[(long long)b*3 + 2] * ROOT_SCALE;

    Xform cur, sv0, sv2, loc;
#pragma unroll
    for (int j = 0; j < NJ; ++j) {
        float4 q = jq[j];                                  // (w,x,y,z)
        float tx = offs[j*16 + 3], ty = offs[j*16 + 7], tz = offs[j*16 + 11];
        quat_rt(q.x, q.y, q.z, q.w, tx, ty, tz, loc);
        if (j == 0) {
            cur = loc;
        } else {
            Xform nxt;
            if (j == 5 || j == 9)        compose(sv2, loc, nxt);   // parent = joint 2
            else if (j == 13 || j == 16) compose(sv0, loc, nxt);   // parent = joint 0
            else                         compose(cur, loc, nxt);   // parent = j-1
            cur = nxt;
        }
        if (j == 0) sv0 = cur;
        if (j == 2) sv2 = cur;
        float4 o;
        o.x = cur.t[0] + rx;
        o.y = cur.t[1] + ry;
        o.z = cur.t[2] + rz;
        o.w = 1.0f;                                        // M[3][3] exactly
        op[j] = o;
    }
}

extern "C" void kernel_launch(void* const* d_in, const int* in_sizes, int n_in,
                              void* d_out, int out_size, void* d_ws, size_t ws_size,
                              hipStream_t stream) {
    const float* root  = (const float*)d_in[0];  // (B,3)
    const float* joint = (const float*)d_in[1];  // (B,76)
    const float* offs  = (const float*)d_in[2];  // (19,4,4)
    float* out = (float*)d_out;                  // (B,19,4)
    const int batch = in_sizes[1] / (NJ * 4);
    const int grid = (batch + BLOCK - 1) / BLOCK;
    fk_kernel<<<grid, BLOCK, 0, stream>>>(root, joint, offs, out, batch);
}